// Round 7
// baseline (223.175 us; speedup 1.0000x reference)
//
#include <hip/hip_runtime.h>
#include <math.h>
#include <stdint.h>

#define Bn 131072
#define Dn 64
#define Kn 4096
#define TK 64              // codes per k-tile
#define NKT (Kn / TK)      // 64 tiles
#define TPR 4              // tiles per round
#define NRD (NKT / TPR)    // 16 rounds

typedef _Float16 f16x8 __attribute__((ext_vector_type(8)));
typedef float f32x4 __attribute__((ext_vector_type(4)));

__device__ __forceinline__ unsigned umn(unsigned a, unsigned b) { return a < b ? a : b; }
// v_med3_u32 exists on CDNA; LLVM won't pattern-match generic int med3, so asm.
__device__ __forceinline__ unsigned umed3(unsigned a, unsigned b, unsigned c) {
  unsigned d;
  asm("v_med3_u32 %0, %1, %2, %3" : "=v"(d) : "v"(a), "v"(b), "v"(c));
  return d;
}

__device__ __forceinline__ void stage16(const void* g, void* l) {
  // global -> LDS direct DMA, 16 B/lane; LDS dest = wave-uniform base + lane*16.
  __builtin_amdgcn_global_load_lds((const __attribute__((address_space(1))) unsigned int*)g,
                                   (__attribute__((address_space(3))) unsigned int*)l,
                                   16, 0, 0);
}

// ---- pre-kernel: codebook f32 -> f16(x4096, RNE) swizzled tile image in ws ----
// Layout: byte = kt*8192 + n*128 + ((p ^ (n&7))<<4), code = kt*64+n, dims p*8..p*8+7.
// Identical RNE conversion to the original in-block staging -> identical scores.
__global__ __launch_bounds__(256) void cvt_cb(const float* __restrict__ cb,
                                              unsigned char* __restrict__ img) {
  int u = blockIdx.x * 256 + threadIdx.x;   // 0..32767 units of 8 dims
  int g = u >> 3;                           // code 0..4095
  int p = u & 7;                            // dim unit
  int kt = g >> 6;
  int n = g & 63;
  const float4* s = (const float4*)(cb + (size_t)g * Dn + p * 8);
  float4 c0 = s[0], c1 = s[1];
  f16x8 h;
  h[0] = (_Float16)(c0.x * 4096.f); h[1] = (_Float16)(c0.y * 4096.f);
  h[2] = (_Float16)(c0.z * 4096.f); h[3] = (_Float16)(c0.w * 4096.f);
  h[4] = (_Float16)(c1.x * 4096.f); h[5] = (_Float16)(c1.y * 4096.f);
  h[6] = (_Float16)(c1.z * 4096.f); h[7] = (_Float16)(c1.w * 4096.f);
  *(f16x8*)(img + (size_t)kt * 8192 + n * 128 + ((p ^ (n & 7)) << 4)) = h;
}

// 512 thr / 8 waves / 256 rows / 32 rows/wave; 4-tile rounds, 2x32 KiB LDS dbuf,
// 1 barrier + 1 vmcnt(0) per round (R6 skeleton). NEW: the tile compute is
// t-granular — per t-step {2 ds_read_b128 -> 4 MFMA (setprio) -> 8-score
// med3-insert} — so no pipe phase is long enough for the 4 waves/SIMD to
// serialize on one unit; launch_bounds(512,2) frees the register allocator
// (the old (512,4)=64-reg cap made cross-phase pipelining impossible).
// Top-2 insert k2=med3(k1,k2,key), k1=min(k1,key) is the exact 2-smallest
// multiset update -> bit-identical candidates to the pair-sort network.
// score_collect = 256 + 4096*(-2 z.e); tag=(t<<6)|kt (8 bits exact);
// exact np-semantics recheck picks the final winner.
__global__ __launch_bounds__(512, 2) void vq_main(const float* __restrict__ z,
                                                  const float* __restrict__ cb,
                                                  const unsigned char* __restrict__ img,
                                                  float* __restrict__ out) {
  __shared__ __align__(16) unsigned char smem[66560];
  unsigned char* bufA = smem;            // 32 KiB: tiles of even rounds
  unsigned char* bufB = smem + 32768;    // 32 KiB: tiles of odd rounds
  const int tid = threadIdx.x;
  const int lane = tid & 63;
  const int w = tid >> 6;             // wave 0..7
  const int q = lane >> 4;
  const int col = lane & 15;
  const int row0 = blockIdx.x * 256;

  // prologue: start round-0's 4 tile DMAs before the A-fragment loads
  const unsigned char* wsrc = img + tid * 16;  // per-thread 16B slot within a tile
#pragma unroll
  for (int j = 0; j < TPR; ++j)
    stage16(wsrc + (size_t)j * 8192, bufA + j * 8192 + tid * 16);

  // ---- A fragments: f16(-2*z), register-resident; wave w owns rows w*32..+32
  f16x8 A[2][2];
#pragma unroll
  for (int i = 0; i < 2; ++i)
#pragma unroll
    for (int c = 0; c < 2; ++c) {
      const float* zp = z + (size_t)(row0 + w * 32 + i * 16 + col) * Dn + c * 32 + q * 8;
      float4 x0 = *(const float4*)zp;
      float4 x1 = *(const float4*)(zp + 4);
      f16x8 a;
      a[0] = (_Float16)(-2.f * x0.x); a[1] = (_Float16)(-2.f * x0.y);
      a[2] = (_Float16)(-2.f * x0.z); a[3] = (_Float16)(-2.f * x0.w);
      a[4] = (_Float16)(-2.f * x1.x); a[5] = (_Float16)(-2.f * x1.y);
      a[6] = (_Float16)(-2.f * x1.z); a[7] = (_Float16)(-2.f * x1.w);
      A[i][c] = a;
    }

  unsigned k1[2][4], k2[2][4];
#pragma unroll
  for (int i = 0; i < 2; ++i)
#pragma unroll
    for (int r = 0; r < 4; ++r) { k1[i][r] = 0xFFFFFFFFu; k2[i][r] = 0xFFFFFFFFu; }
  unsigned tg[4] = {0u << 6, 1u << 6, 2u << 6, 3u << 6};  // tag=(t<<6)|kt, ++/tile
  const f32x4 c256 = {256.f, 256.f, 256.f, 256.f};
  const int xu = (col & 7) << 4;       // lane's unit-XOR byte offset

  for (int rd = 0; rd < NRD; ++rd) {
    unsigned char* bcur = (rd & 1) ? bufB : bufA;
    unsigned char* bnxt = (rd & 1) ? bufA : bufB;
    // this round's 4 DMAs were issued last round (or prologue) and are the only
    // outstanding vm ops -> vmcnt(0) waits for them; barrier makes all waves'
    // chunks visible AND proves every wave finished reading bnxt (prev round).
    asm volatile("s_waitcnt vmcnt(0)" ::: "memory");
    __builtin_amdgcn_s_barrier();
    __builtin_amdgcn_sched_barrier(0);
    if (rd + 1 < NRD) {
#pragma unroll
      for (int j = 0; j < TPR; ++j)
        stage16(wsrc + ((size_t)(rd + 1) * TPR + j) * 8192, bnxt + j * 8192 + tid * 16);
    }

    // 4 tiles, t-granular interleave, no sync inside the round.
#pragma unroll
    for (int j = 0; j < TPR; ++j) {
      const unsigned char* tb = bcur + j * 8192;
#pragma unroll
      for (int t = 0; t < 4; ++t) {
        const int rowb = (t * 16 + col) * 128;
        // B[k=q*8+jj][ncode=t*16+col]; unit (c*4+q) ^ (col&7)
        f16x8 B0 = *(const f16x8*)(tb + rowb + ((q << 4) ^ xu));
        f16x8 B1 = *(const f16x8*)(tb + rowb + (((4 + q) << 4) ^ xu));
        __builtin_amdgcn_s_setprio(1);
        f32x4 a0 = __builtin_amdgcn_mfma_f32_16x16x32_f16(A[0][0], B0, c256, 0, 0, 0);
        f32x4 a1 = __builtin_amdgcn_mfma_f32_16x16x32_f16(A[1][0], B0, c256, 0, 0, 0);
        a0 = __builtin_amdgcn_mfma_f32_16x16x32_f16(A[0][1], B1, a0, 0, 0, 0);
        a1 = __builtin_amdgcn_mfma_f32_16x16x32_f16(A[1][1], B1, a1, 0, 0, 0);
        __builtin_amdgcn_s_setprio(0);
        // exact top-2 insert per slot (scores > 0: uint cmp == float cmp;
        // truncation commutes with min): k2=med3(k1,k2,key); k1=min(k1,key)
        const unsigned tgv = tg[t];
#pragma unroll
        for (int r = 0; r < 4; ++r) {
          unsigned key0 = (__float_as_uint(a0[r]) & 0xFFFFFF00u) | tgv;
          k2[0][r] = umed3(k1[0][r], k2[0][r], key0);
          k1[0][r] = umn(k1[0][r], key0);
          unsigned key1 = (__float_as_uint(a1[r]) & 0xFFFFFF00u) | tgv;
          k2[1][r] = umed3(k1[1][r], k2[1][r], key1);
          k1[1][r] = umn(k1[1][r], key1);
        }
      }
#pragma unroll
      for (int t = 0; t < 4; ++t) tg[t] += 1;   // kt lives in low 6 bits
    }
  }

  __syncthreads();                 // ALL waves' compute done; reuse LDS for dump
  // padded stride 33 ints: bank-conflict-free per-row candidate scan
  unsigned* dmp = (unsigned*)smem;
#pragma unroll
  for (int i = 0; i < 2; ++i)
#pragma unroll
    for (int r = 0; r < 4; ++r) {
      int rb = w * 32 + i * 16 + q * 4 + r;  // C-layout: row = quad*4 + reg
      dmp[rb * 33 + col * 2] = k1[i][r];
      dmp[rb * 33 + col * 2 + 1] = k2[i][r];
    }
  __syncthreads();

  // ---- final: per-row margin filter + exact np-semantics recheck ----
  // 2 threads per row: half h scans candidates [h*16, h*16+16), shfl combine.
  {
    const int rl = tid >> 1;          // row in block (256 rows, 512 threads)
    const int half = tid & 1;
    const unsigned* keys = dmp + rl * 33 + half * 16;
    unsigned mk = 0xFFFFFFFFu;
    for (int j = 0; j < 16; ++j) mk = umn(mk, keys[j]);
    // per-half lim >= global lim -> per-half candidate set is a superset; the
    // true winner always passes its own half's filter (margin logic unchanged).
    // scaled margin 0.5 = 1.2e-4 unscaled: covers f16 cvt noise (RNE, ~5e-7),
    // e2 omission (2.6e-6), key truncation (1.9e-6), np fp32-grid ulp (7.6e-6)
    const float lim = __uint_as_float(mk & 0xFFFFFF00u) + 0.5f;

    const float4* zr4 = (const float4*)(z + (size_t)(row0 + rl) * Dn);

    // z2: np-pairwise grouping (argmin invariant to z2 rounding; keep identical)
    float r8[8];
#pragma unroll
    for (int g = 0; g < 2; ++g) {
      float4 v = zr4[g]; int j = g * 4;
      r8[j + 0] = __fmul_rn(v.x, v.x); r8[j + 1] = __fmul_rn(v.y, v.y);
      r8[j + 2] = __fmul_rn(v.z, v.z); r8[j + 3] = __fmul_rn(v.w, v.w);
    }
#pragma unroll
    for (int g = 2; g < 16; ++g) {
      float4 v = zr4[g]; int j = (g & 1) * 4;
      r8[j + 0] = __fadd_rn(r8[j + 0], __fmul_rn(v.x, v.x));
      r8[j + 1] = __fadd_rn(r8[j + 1], __fmul_rn(v.y, v.y));
      r8[j + 2] = __fadd_rn(r8[j + 2], __fmul_rn(v.z, v.z));
      r8[j + 3] = __fadd_rn(r8[j + 3], __fmul_rn(v.w, v.w));
    }
    float z2f = __fadd_rn(__fadd_rn(__fadd_rn(r8[0], r8[1]), __fadd_rn(r8[2], r8[3])),
                          __fadd_rn(__fadd_rn(r8[4], r8[5]), __fadd_rn(r8[6], r8[7])));

    float bq = INFINITY; int bc = Kn;
    for (int j = 0; j < 16; ++j) {
      unsigned key = keys[j];
      float sc = __uint_as_float(key & 0xFFFFFF00u);
      if (sc > lim) continue;
      int c2 = half * 16 + j;
      int tag = (int)(key & 0xFFu);             // (t<<6)|kt
      int code = (tag & 63) * 64 + (tag >> 6) * 16 + (c2 >> 1);
      const float4* cr = (const float4*)(cb + (size_t)code * Dn);
      double ze = 0.0;
      float e8[8];
#pragma unroll
      for (int g = 0; g < 16; ++g) {
        float4 ev = cr[g]; float4 zv = zr4[g];
        ze += (double)ev.x * (double)zv.x + (double)ev.y * (double)zv.y +
              (double)ev.z * (double)zv.z + (double)ev.w * (double)zv.w;
        int jj = (g & 1) * 4;
        if (g < 2) {
          e8[jj + 0] = __fmul_rn(ev.x, ev.x); e8[jj + 1] = __fmul_rn(ev.y, ev.y);
          e8[jj + 2] = __fmul_rn(ev.z, ev.z); e8[jj + 3] = __fmul_rn(ev.w, ev.w);
        } else {
          e8[jj + 0] = __fadd_rn(e8[jj + 0], __fmul_rn(ev.x, ev.x));
          e8[jj + 1] = __fadd_rn(e8[jj + 1], __fmul_rn(ev.y, ev.y));
          e8[jj + 2] = __fadd_rn(e8[jj + 2], __fmul_rn(ev.z, ev.z));
          e8[jj + 3] = __fadd_rn(e8[jj + 3], __fmul_rn(ev.w, ev.w));
        }
      }
      float e2f = __fadd_rn(__fadd_rn(__fadd_rn(e8[0], e8[1]), __fadd_rn(e8[2], e8[3])),
                            __fadd_rn(__fadd_rn(e8[4], e8[5]), __fadd_rn(e8[6], e8[7])));
      // np semantics: qv = fl32( fl32(z2 + e2) - fl32(2*ze) )
      float zef = (float)ze;
      float t1 = __fadd_rn(z2f, e2f);
      float t2 = __fmul_rn(2.0f, zef);
      float qv = __fadd_rn(t1, -t2);
      if (qv < bq || (qv == bq && code < bc)) { bq = qv; bc = code; }
    }
    // combine the two halves (adjacent lanes, same wave)
    float obq = __shfl_xor(bq, 1);
    int obc = __shfl_xor(bc, 1);
    if (obq < bq || (obq == bq && obc < bc)) { bq = obq; bc = obc; }
    if (half == 0) {
      ((int*)(smem + 65536))[rl] = bc;
      out[(size_t)Bn * Dn + row0 + rl] = (float)bc;
    }
  }
  __syncthreads();

  // ---- gather z_q = cb[winner], coalesced float4 ----
  {
    const float4* cb4 = (const float4*)cb;
    float4* out4 = (float4*)out;
    const int* wc = (const int*)(smem + 65536);
#pragma unroll
    for (int i = 0; i < 8; ++i) {
      int t = i * 512 + tid;
      int r = t >> 4, c2 = t & 15;
      int wn = wc[r];
      out4[(size_t)(row0 + r) * 16 + c2] = cb4[(size_t)wn * 16 + c2];
    }
  }
}

extern "C" void kernel_launch(void* const* d_in, const int* in_sizes, int n_in,
                              void* d_out, int out_size, void* d_ws, size_t ws_size,
                              hipStream_t stream) {
  const float* z = (const float*)d_in[0];
  const float* cb = (const float*)d_in[1];
  float* out = (float*)d_out;
  unsigned char* img = (unsigned char*)d_ws;   // needs 4096*64*2 = 512 KiB
  cvt_cb<<<128, 256, 0, stream>>>(cb, img);
  vq_main<<<Bn / 256, 512, 0, stream>>>(z, cb, img, out);
}

// Round 8
// 210.831 us; speedup vs baseline: 1.0585x; 1.0585x over previous
//
#include <hip/hip_runtime.h>
#include <math.h>
#include <stdint.h>

#define Bn 131072
#define Dn 64
#define Kn 4096
#define TK 64              // codes per k-tile
#define NKT (Kn / TK)      // 64 tiles
#define TPR 4              // tiles per round
#define NRD (NKT / TPR)    // 16 rounds

typedef _Float16 f16x8 __attribute__((ext_vector_type(8)));
typedef float f32x4 __attribute__((ext_vector_type(4)));

__device__ __forceinline__ unsigned umn(unsigned a, unsigned b) { return a < b ? a : b; }
// v_med3_u32 exists on CDNA; LLVM won't pattern-match generic int med3, so asm.
__device__ __forceinline__ unsigned umed3(unsigned a, unsigned b, unsigned c) {
  unsigned d;
  asm("v_med3_u32 %0, %1, %2, %3" : "=v"(d) : "v"(a), "v"(b), "v"(c));
  return d;
}

__device__ __forceinline__ void stage16(const void* g, void* l) {
  // global -> LDS direct DMA, 16 B/lane; LDS dest = wave-uniform base + lane*16.
  __builtin_amdgcn_global_load_lds((const __attribute__((address_space(1))) unsigned int*)g,
                                   (__attribute__((address_space(3))) unsigned int*)l,
                                   16, 0, 0);
}

// ---- pre-kernel: codebook f32 -> f16(x4096, RNE) swizzled tile image in ws ----
// Layout: byte = kt*8192 + n*128 + ((p ^ (n&7))<<4), code = kt*64+n, dims p*8..p*8+7.
// Identical RNE conversion to the original in-block staging -> identical scores.
__global__ __launch_bounds__(256) void cvt_cb(const float* __restrict__ cb,
                                              unsigned char* __restrict__ img) {
  int u = blockIdx.x * 256 + threadIdx.x;   // 0..32767 units of 8 dims
  int g = u >> 3;                           // code 0..4095
  int p = u & 7;                            // dim unit
  int kt = g >> 6;
  int n = g & 63;
  const float4* s = (const float4*)(cb + (size_t)g * Dn + p * 8);
  float4 c0 = s[0], c1 = s[1];
  f16x8 h;
  h[0] = (_Float16)(c0.x * 4096.f); h[1] = (_Float16)(c0.y * 4096.f);
  h[2] = (_Float16)(c0.z * 4096.f); h[3] = (_Float16)(c0.w * 4096.f);
  h[4] = (_Float16)(c1.x * 4096.f); h[5] = (_Float16)(c1.y * 4096.f);
  h[6] = (_Float16)(c1.z * 4096.f); h[7] = (_Float16)(c1.w * 4096.f);
  *(f16x8*)(img + (size_t)kt * 8192 + n * 128 + ((p ^ (n & 7)) << 4)) = h;
}

// One round (4 tiles): vmcnt(0)+barrier, stage next round's tiles into WB,
// compute TPR tiles from RB. RB/WB are compile-time so EVERY ds_read address is
// base-VGPR + 16-bit immediate offset (zero per-tile address VALU). Per t-step:
// 2 ds_read_b128 -> 4 chained MFMA -> 8 exact single-key top-2 inserts
// (k2=med3(k1,k2,key); k1=min(k1,key)) -> bit-identical candidates to R6.
template <int RB, int WB>
__device__ __forceinline__ void round_body(int rd, int tid,
                                           unsigned char* smem_,
                                           const unsigned char* b0,
                                           const unsigned char* b1,
                                           const unsigned char* wsrc,
                                           const f16x8 (&A)[2][2],
                                           unsigned (&k1)[2][4], unsigned (&k2)[2][4],
                                           unsigned (&tg)[4], const f32x4 c256) {
  // this round's 4 DMAs were issued last round (or prologue) and are the only
  // outstanding vm ops -> vmcnt(0) waits for them; barrier makes all waves'
  // chunks visible AND proves every wave finished reading buffer WB.
  asm volatile("s_waitcnt vmcnt(0)" ::: "memory");
  __builtin_amdgcn_s_barrier();
  __builtin_amdgcn_sched_barrier(0);
  if (rd + 1 < NRD) {
#pragma unroll
    for (int j = 0; j < TPR; ++j)
      stage16(wsrc + ((size_t)(rd + 1) * TPR + j) * 8192, smem_ + WB + j * 8192 + tid * 16);
  }
#pragma unroll
  for (int j = 0; j < TPR; ++j) {
#pragma unroll
    for (int t = 0; t < 4; ++t) {
      const f16x8 B0 = *(const f16x8*)(b0 + RB + j * 8192 + t * 2048);
      const f16x8 B1 = *(const f16x8*)(b1 + RB + j * 8192 + t * 2048);
      f32x4 a0 = __builtin_amdgcn_mfma_f32_16x16x32_f16(A[0][0], B0, c256, 0, 0, 0);
      f32x4 a1 = __builtin_amdgcn_mfma_f32_16x16x32_f16(A[1][0], B0, c256, 0, 0, 0);
      a0 = __builtin_amdgcn_mfma_f32_16x16x32_f16(A[0][1], B1, a0, 0, 0, 0);
      a1 = __builtin_amdgcn_mfma_f32_16x16x32_f16(A[1][1], B1, a1, 0, 0, 0);
      // exact top-2 insert per slot (scores > 0: uint cmp == float cmp;
      // truncation commutes with min): k2=med3(k1,k2,key); k1=min(k1,key)
#pragma unroll
      for (int r = 0; r < 4; ++r) {
        unsigned key0 = (__float_as_uint(a0[r]) & 0xFFFFFF00u) | tg[t];
        k2[0][r] = umed3(k1[0][r], k2[0][r], key0);
        k1[0][r] = umn(k1[0][r], key0);
        unsigned key1 = (__float_as_uint(a1[r]) & 0xFFFFFF00u) | tg[t];
        k2[1][r] = umed3(k1[1][r], k2[1][r], key1);
        k1[1][r] = umn(k1[1][r], key1);
      }
    }
#pragma unroll
    for (int t = 0; t < 4; ++t) tg[t] += 1;   // kt lives in low 6 bits
  }
}

// R6 skeleton: 512 thr / 8 waves / 256 rows / 32 rows/wave; 4-tile rounds,
// 2x32 KiB LDS dbuf, 1 barrier + 1 vmcnt(0) per round; launch_bounds(512,4)
// (R7 showed (512,2) costs a resident block/CU). NEW vs R6: compile-time ds
// offsets (zero addressing VALU), per-t single-key med3 insert, tiny acc live
// set. score_collect = 256 + 4096*(-2 z.e); tag=(t<<6)|kt (8 bits exact);
// exact np-semantics recheck picks the final winner.
__global__ __launch_bounds__(512, 4) void vq_main(const float* __restrict__ z,
                                                  const float* __restrict__ cb,
                                                  const unsigned char* __restrict__ img,
                                                  float* __restrict__ out) {
  __shared__ __align__(16) unsigned char smem[66560];
  const int tid = threadIdx.x;
  const int lane = tid & 63;
  const int w = tid >> 6;             // wave 0..7
  const int q = lane >> 4;
  const int col = lane & 15;
  const int row0 = blockIdx.x * 256;

  // prologue: start round-0's 4 tile DMAs before the A-fragment loads
  const unsigned char* wsrc = img + tid * 16;  // per-thread 16B slot within a tile
#pragma unroll
  for (int j = 0; j < TPR; ++j)
    stage16(wsrc + (size_t)j * 8192, smem + j * 8192 + tid * 16);

  // ---- A fragments: f16(-2*z), register-resident; wave w owns rows w*32..+32
  f16x8 A[2][2];
#pragma unroll
  for (int i = 0; i < 2; ++i)
#pragma unroll
    for (int c = 0; c < 2; ++c) {
      const float* zp = z + (size_t)(row0 + w * 32 + i * 16 + col) * Dn + c * 32 + q * 8;
      float4 x0 = *(const float4*)zp;
      float4 x1 = *(const float4*)(zp + 4);
      f16x8 a;
      a[0] = (_Float16)(-2.f * x0.x); a[1] = (_Float16)(-2.f * x0.y);
      a[2] = (_Float16)(-2.f * x0.z); a[3] = (_Float16)(-2.f * x0.w);
      a[4] = (_Float16)(-2.f * x1.x); a[5] = (_Float16)(-2.f * x1.y);
      a[6] = (_Float16)(-2.f * x1.z); a[7] = (_Float16)(-2.f * x1.w);
      A[i][c] = a;
    }

  unsigned k1[2][4], k2[2][4];
#pragma unroll
  for (int i = 0; i < 2; ++i)
#pragma unroll
    for (int r = 0; r < 4; ++r) { k1[i][r] = 0xFFFFFFFFu; k2[i][r] = 0xFFFFFFFFu; }
  unsigned tg[4] = {0u << 6, 1u << 6, 2u << 6, 3u << 6};  // tag=(t<<6)|kt, ++/tile
  const f32x4 c256 = {256.f, 256.f, 256.f, 256.f};

  // thread-constant LDS base pointers (identical bytes to R6's indexing):
  // read = base + RB + j*8192 + t*2048, base = col*128 + ((u ^ (col&7))<<4)
  const int xu = (col & 7) << 4;
  const unsigned char* b0 = smem + col * 128 + ((q << 4) ^ xu);          // c=0: unit q
  const unsigned char* b1 = smem + col * 128 + (((4 + q) << 4) ^ xu);    // c=1: unit 4+q

#pragma unroll 1
  for (int rp = 0; rp < NRD / 2; ++rp) {
    round_body<0, 32768>(2 * rp, tid, smem, b0, b1, wsrc, A, k1, k2, tg, c256);
    round_body<32768, 0>(2 * rp + 1, tid, smem, b0, b1, wsrc, A, k1, k2, tg, c256);
  }

  __syncthreads();                 // ALL waves' compute done; reuse LDS for dump
  // padded stride 33 ints: bank-conflict-free per-row candidate scan
  unsigned* dmp = (unsigned*)smem;
#pragma unroll
  for (int i = 0; i < 2; ++i)
#pragma unroll
    for (int r = 0; r < 4; ++r) {
      int rb = w * 32 + i * 16 + q * 4 + r;  // C-layout: row = quad*4 + reg
      dmp[rb * 33 + col * 2] = k1[i][r];
      dmp[rb * 33 + col * 2 + 1] = k2[i][r];
    }
  __syncthreads();

  // ---- final: per-row margin filter + exact np-semantics recheck ----
  // 2 threads per row: half h scans candidates [h*16, h*16+16), shfl combine.
  {
    const int rl = tid >> 1;          // row in block (256 rows, 512 threads)
    const int half = tid & 1;
    const unsigned* keys = dmp + rl * 33 + half * 16;
    unsigned mk = 0xFFFFFFFFu;
    for (int j = 0; j < 16; ++j) mk = umn(mk, keys[j]);
    // per-half lim >= global lim -> per-half candidate set is a superset; the
    // true winner always passes its own half's filter (margin logic unchanged).
    // scaled margin 0.5 = 1.2e-4 unscaled: covers f16 cvt noise (RNE, ~5e-7),
    // e2 omission (2.6e-6), key truncation (1.9e-6), np fp32-grid ulp (7.6e-6)
    const float lim = __uint_as_float(mk & 0xFFFFFF00u) + 0.5f;

    const float4* zr4 = (const float4*)(z + (size_t)(row0 + rl) * Dn);

    // z2: np-pairwise grouping (argmin invariant to z2 rounding; keep identical)
    float r8[8];
#pragma unroll
    for (int g = 0; g < 2; ++g) {
      float4 v = zr4[g]; int j = g * 4;
      r8[j + 0] = __fmul_rn(v.x, v.x); r8[j + 1] = __fmul_rn(v.y, v.y);
      r8[j + 2] = __fmul_rn(v.z, v.z); r8[j + 3] = __fmul_rn(v.w, v.w);
    }
#pragma unroll
    for (int g = 2; g < 16; ++g) {
      float4 v = zr4[g]; int j = (g & 1) * 4;
      r8[j + 0] = __fadd_rn(r8[j + 0], __fmul_rn(v.x, v.x));
      r8[j + 1] = __fadd_rn(r8[j + 1], __fmul_rn(v.y, v.y));
      r8[j + 2] = __fadd_rn(r8[j + 2], __fmul_rn(v.z, v.z));
      r8[j + 3] = __fadd_rn(r8[j + 3], __fmul_rn(v.w, v.w));
    }
    float z2f = __fadd_rn(__fadd_rn(__fadd_rn(r8[0], r8[1]), __fadd_rn(r8[2], r8[3])),
                          __fadd_rn(__fadd_rn(r8[4], r8[5]), __fadd_rn(r8[6], r8[7])));

    float bq = INFINITY; int bc = Kn;
    for (int j = 0; j < 16; ++j) {
      unsigned key = keys[j];
      float sc = __uint_as_float(key & 0xFFFFFF00u);
      if (sc > lim) continue;
      int c2 = half * 16 + j;
      int tag = (int)(key & 0xFFu);             // (t<<6)|kt
      int code = (tag & 63) * 64 + (tag >> 6) * 16 + (c2 >> 1);
      const float4* cr = (const float4*)(cb + (size_t)code * Dn);
      double ze = 0.0;
      float e8[8];
#pragma unroll
      for (int g = 0; g < 16; ++g) {
        float4 ev = cr[g]; float4 zv = zr4[g];
        ze += (double)ev.x * (double)zv.x + (double)ev.y * (double)zv.y +
              (double)ev.z * (double)zv.z + (double)ev.w * (double)zv.w;
        int jj = (g & 1) * 4;
        if (g < 2) {
          e8[jj + 0] = __fmul_rn(ev.x, ev.x); e8[jj + 1] = __fmul_rn(ev.y, ev.y);
          e8[jj + 2] = __fmul_rn(ev.z, ev.z); e8[jj + 3] = __fmul_rn(ev.w, ev.w);
        } else {
          e8[jj + 0] = __fadd_rn(e8[jj + 0], __fmul_rn(ev.x, ev.x));
          e8[jj + 1] = __fadd_rn(e8[jj + 1], __fmul_rn(ev.y, ev.y));
          e8[jj + 2] = __fadd_rn(e8[jj + 2], __fmul_rn(ev.z, ev.z));
          e8[jj + 3] = __fadd_rn(e8[jj + 3], __fmul_rn(ev.w, ev.w));
        }
      }
      float e2f = __fadd_rn(__fadd_rn(__fadd_rn(e8[0], e8[1]), __fadd_rn(e8[2], e8[3])),
                            __fadd_rn(__fadd_rn(e8[4], e8[5]), __fadd_rn(e8[6], e8[7])));
      // np semantics: qv = fl32( fl32(z2 + e2) - fl32(2*ze) )
      float zef = (float)ze;
      float t1 = __fadd_rn(z2f, e2f);
      float t2 = __fmul_rn(2.0f, zef);
      float qv = __fadd_rn(t1, -t2);
      if (qv < bq || (qv == bq && code < bc)) { bq = qv; bc = code; }
    }
    // combine the two halves (adjacent lanes, same wave)
    float obq = __shfl_xor(bq, 1);
    int obc = __shfl_xor(bc, 1);
    if (obq < bq || (obq == bq && obc < bc)) { bq = obq; bc = obc; }
    if (half == 0) {
      ((int*)(smem + 65536))[rl] = bc;
      out[(size_t)Bn * Dn + row0 + rl] = (float)bc;
    }
  }
  __syncthreads();

  // ---- gather z_q = cb[winner], coalesced float4 ----
  {
    const float4* cb4 = (const float4*)cb;
    float4* out4 = (float4*)out;
    const int* wc = (const int*)(smem + 65536);
#pragma unroll
    for (int i = 0; i < 8; ++i) {
      int t = i * 512 + tid;
      int r = t >> 4, c2 = t & 15;
      int wn = wc[r];
      out4[(size_t)(row0 + r) * 16 + c2] = cb4[(size_t)wn * 16 + c2];
    }
  }
}

extern "C" void kernel_launch(void* const* d_in, const int* in_sizes, int n_in,
                              void* d_out, int out_size, void* d_ws, size_t ws_size,
                              hipStream_t stream) {
  const float* z = (const float*)d_in[0];
  const float* cb = (const float*)d_in[1];
  float* out = (float*)d_out;
  unsigned char* img = (unsigned char*)d_ws;   // needs 4096*64*2 = 512 KiB
  cvt_cb<<<128, 256, 0, stream>>>(cb, img);
  vq_main<<<Bn / 256, 512, 0, stream>>>(z, cb, img, out);
}

// Round 9
// 197.875 us; speedup vs baseline: 1.1279x; 1.0655x over previous
//
#include <hip/hip_runtime.h>
#include <math.h>
#include <stdint.h>

#define Bn 131072
#define Dn 64
#define Kn 4096
#define TK 64              // codes per k-tile
#define NKT (Kn / TK)      // 64 tiles
#define TPR 4              // tiles per round
#define NRD (NKT / TPR)    // 16 rounds

typedef _Float16 f16x8 __attribute__((ext_vector_type(8)));
typedef float f32x4 __attribute__((ext_vector_type(4)));

__device__ __forceinline__ unsigned umn(unsigned a, unsigned b) { return a < b ? a : b; }
// v_med3_u32 exists on CDNA; LLVM won't pattern-match generic int med3, so asm.
__device__ __forceinline__ unsigned umed3(unsigned a, unsigned b, unsigned c) {
  unsigned d;
  asm("v_med3_u32 %0, %1, %2, %3" : "=v"(d) : "v"(a), "v"(b), "v"(c));
  return d;
}

__device__ __forceinline__ void stage16(const void* g, void* l) {
  // global -> LDS direct DMA, 16 B/lane; LDS dest = wave-uniform base + lane*16.
  __builtin_amdgcn_global_load_lds((const __attribute__((address_space(1))) unsigned int*)g,
                                   (__attribute__((address_space(3))) unsigned int*)l,
                                   16, 0, 0);
}

// ---- pre-kernel: codebook f32 -> f16(x4096, RNE) swizzled tile image in ws ----
// Layout: byte = kt*8192 + n*128 + ((p ^ (n&7))<<4), code = kt*64+n, dims p*8..p*8+7.
// Identical RNE conversion to the original in-block staging -> identical scores.
__global__ __launch_bounds__(256) void cvt_cb(const float* __restrict__ cb,
                                              unsigned char* __restrict__ img) {
  int u = blockIdx.x * 256 + threadIdx.x;   // 0..32767 units of 8 dims
  int g = u >> 3;                           // code 0..4095
  int p = u & 7;                            // dim unit
  int kt = g >> 6;
  int n = g & 63;
  const float4* s = (const float4*)(cb + (size_t)g * Dn + p * 8);
  float4 c0 = s[0], c1 = s[1];
  f16x8 h;
  h[0] = (_Float16)(c0.x * 4096.f); h[1] = (_Float16)(c0.y * 4096.f);
  h[2] = (_Float16)(c0.z * 4096.f); h[3] = (_Float16)(c0.w * 4096.f);
  h[4] = (_Float16)(c1.x * 4096.f); h[5] = (_Float16)(c1.y * 4096.f);
  h[6] = (_Float16)(c1.z * 4096.f); h[7] = (_Float16)(c1.w * 4096.f);
  *(f16x8*)(img + (size_t)kt * 8192 + n * 128 + ((p ^ (n & 7)) << 4)) = h;
}

// One round (4 tiles): vmcnt(0)+barrier, stage next round's tiles into WB
// (2 DMA slots per tile per thread: 256 thr x 32 B = 8 KiB), compute TPR tiles
// from RB. RB/WB compile-time -> every ds_read is base-VGPR + 16-bit immediate.
// Per t-step: 2 ds_read_b128 -> 8 MFMA (i=0..3 x c=0,1; each B-frag feeds 4
// MFMAs) -> 16 exact single-key top-2 inserts (k2=med3(k1,k2,key);
// k1=min(k1,key)).
template <int RB, int WB>
__device__ __forceinline__ void round_body(int rd, int tid,
                                           unsigned char* smem_,
                                           const unsigned char* b0,
                                           const unsigned char* b1,
                                           const unsigned char* wsrc,
                                           const f16x8 (&A)[4][2],
                                           unsigned (&k1)[4][4], unsigned (&k2)[4][4],
                                           unsigned (&tg)[4], const f32x4 c256) {
  // this round's 8 DMAs were issued last round (or prologue) and are the only
  // outstanding vm ops -> vmcnt(0) waits for them; barrier makes all waves'
  // chunks visible AND proves every wave finished reading buffer WB.
  asm volatile("s_waitcnt vmcnt(0)" ::: "memory");
  __builtin_amdgcn_s_barrier();
  __builtin_amdgcn_sched_barrier(0);
  if (rd + 1 < NRD) {
#pragma unroll
    for (int j = 0; j < TPR; ++j) {
      const unsigned char* gs = wsrc + ((size_t)(rd + 1) * TPR + j) * 8192;
      stage16(gs, smem_ + WB + j * 8192 + tid * 16);
      stage16(gs + 4096, smem_ + WB + j * 8192 + 4096 + tid * 16);
    }
  }
#pragma unroll
  for (int j = 0; j < TPR; ++j) {
#pragma unroll
    for (int t = 0; t < 4; ++t) {
      const f16x8 B0 = *(const f16x8*)(b0 + RB + j * 8192 + t * 2048);
      const f16x8 B1 = *(const f16x8*)(b1 + RB + j * 8192 + t * 2048);
      f32x4 a0 = __builtin_amdgcn_mfma_f32_16x16x32_f16(A[0][0], B0, c256, 0, 0, 0);
      f32x4 a1 = __builtin_amdgcn_mfma_f32_16x16x32_f16(A[1][0], B0, c256, 0, 0, 0);
      f32x4 a2 = __builtin_amdgcn_mfma_f32_16x16x32_f16(A[2][0], B0, c256, 0, 0, 0);
      f32x4 a3 = __builtin_amdgcn_mfma_f32_16x16x32_f16(A[3][0], B0, c256, 0, 0, 0);
      a0 = __builtin_amdgcn_mfma_f32_16x16x32_f16(A[0][1], B1, a0, 0, 0, 0);
      a1 = __builtin_amdgcn_mfma_f32_16x16x32_f16(A[1][1], B1, a1, 0, 0, 0);
      a2 = __builtin_amdgcn_mfma_f32_16x16x32_f16(A[2][1], B1, a2, 0, 0, 0);
      a3 = __builtin_amdgcn_mfma_f32_16x16x32_f16(A[3][1], B1, a3, 0, 0, 0);
      // exact top-2 insert per slot (scores > 0: uint cmp == float cmp;
      // truncation commutes with min): k2=med3(k1,k2,key); k1=min(k1,key)
#pragma unroll
      for (int r = 0; r < 4; ++r) {
        unsigned key0 = (__float_as_uint(a0[r]) & 0xFFFFFF00u) | tg[t];
        k2[0][r] = umed3(k1[0][r], k2[0][r], key0);
        k1[0][r] = umn(k1[0][r], key0);
        unsigned key1 = (__float_as_uint(a1[r]) & 0xFFFFFF00u) | tg[t];
        k2[1][r] = umed3(k1[1][r], k2[1][r], key1);
        k1[1][r] = umn(k1[1][r], key1);
        unsigned key2 = (__float_as_uint(a2[r]) & 0xFFFFFF00u) | tg[t];
        k2[2][r] = umed3(k1[2][r], k2[2][r], key2);
        k1[2][r] = umn(k1[2][r], key2);
        unsigned key3 = (__float_as_uint(a3[r]) & 0xFFFFFF00u) | tg[t];
        k2[3][r] = umed3(k1[3][r], k2[3][r], key3);
        k1[3][r] = umn(k1[3][r], key3);
      }
    }
#pragma unroll
    for (int t = 0; t < 4; ++t) tg[t] += 1;   // kt lives in low 6 bits
  }
}

// 256 thr / 4 waves / 256 rows per block, 64 ROWS PER WAVE (the lever: per-wave
// LDS codebook broadcast is 512 KiB regardless of rows owned, so rows/wave
// sets the per-CU LDS-read floor; 64 r/w halves it vs 32 r/w, and each B-frag
// now feeds 4 MFMAs -> ILP covers ds latency). Grid 512 -> 2 independent
// blocks/CU (133 KiB LDS). 4-tile rounds, 2x32 KiB dbuf, 1 barrier + 1
// vmcnt(0) per round. score_collect = 256 + 4096*(-2 z.e); tag=(t<<6)|kt;
// exact np-semantics recheck picks the final winner.
__global__ __launch_bounds__(256, 2) void vq_main(const float* __restrict__ z,
                                                  const float* __restrict__ cb,
                                                  const unsigned char* __restrict__ img,
                                                  float* __restrict__ out) {
  __shared__ __align__(16) unsigned char smem[66560];
  const int tid = threadIdx.x;
  const int lane = tid & 63;
  const int w = tid >> 6;             // wave 0..3
  const int q = lane >> 4;
  const int col = lane & 15;
  const int row0 = blockIdx.x * 256;

  // prologue: start round-0's 4 tile DMAs (2 slots/tile/thread)
  const unsigned char* wsrc = img + tid * 16;
#pragma unroll
  for (int j = 0; j < TPR; ++j) {
    stage16(wsrc + (size_t)j * 8192, smem + j * 8192 + tid * 16);
    stage16(wsrc + (size_t)j * 8192 + 4096, smem + j * 8192 + 4096 + tid * 16);
  }

  // ---- A fragments: f16(-2*z), register-resident; wave w owns rows w*64..+64
  f16x8 A[4][2];
#pragma unroll
  for (int i = 0; i < 4; ++i)
#pragma unroll
    for (int c = 0; c < 2; ++c) {
      const float* zp = z + (size_t)(row0 + w * 64 + i * 16 + col) * Dn + c * 32 + q * 8;
      float4 x0 = *(const float4*)zp;
      float4 x1 = *(const float4*)(zp + 4);
      f16x8 a;
      a[0] = (_Float16)(-2.f * x0.x); a[1] = (_Float16)(-2.f * x0.y);
      a[2] = (_Float16)(-2.f * x0.z); a[3] = (_Float16)(-2.f * x0.w);
      a[4] = (_Float16)(-2.f * x1.x); a[5] = (_Float16)(-2.f * x1.y);
      a[6] = (_Float16)(-2.f * x1.z); a[7] = (_Float16)(-2.f * x1.w);
      A[i][c] = a;
    }

  unsigned k1[4][4], k2[4][4];
#pragma unroll
  for (int i = 0; i < 4; ++i)
#pragma unroll
    for (int r = 0; r < 4; ++r) { k1[i][r] = 0xFFFFFFFFu; k2[i][r] = 0xFFFFFFFFu; }
  unsigned tg[4] = {0u << 6, 1u << 6, 2u << 6, 3u << 6};  // tag=(t<<6)|kt, ++/tile
  const f32x4 c256 = {256.f, 256.f, 256.f, 256.f};

  // thread-constant LDS base pointers (identical bytes to R6/R8 indexing):
  // read = base + RB + j*8192 + t*2048, base = col*128 + ((u ^ (col&7))<<4)
  const int xu = (col & 7) << 4;
  const unsigned char* b0 = smem + col * 128 + ((q << 4) ^ xu);          // c=0: unit q
  const unsigned char* b1 = smem + col * 128 + (((4 + q) << 4) ^ xu);    // c=1: unit 4+q

#pragma unroll 1
  for (int rp = 0; rp < NRD / 2; ++rp) {
    round_body<0, 32768>(2 * rp, tid, smem, b0, b1, wsrc, A, k1, k2, tg, c256);
    round_body<32768, 0>(2 * rp + 1, tid, smem, b0, b1, wsrc, A, k1, k2, tg, c256);
  }

  __syncthreads();                 // ALL waves' compute done; reuse LDS for dump
  // padded stride 33 ints: bank-conflict-free per-row candidate scan
  unsigned* dmp = (unsigned*)smem;
#pragma unroll
  for (int i = 0; i < 4; ++i)
#pragma unroll
    for (int r = 0; r < 4; ++r) {
      int rb = w * 64 + i * 16 + q * 4 + r;  // C-layout: row = quad*4 + reg
      dmp[rb * 33 + col * 2] = k1[i][r];
      dmp[rb * 33 + col * 2 + 1] = k2[i][r];
    }
  __syncthreads();

  // ---- final: per-row margin filter + exact np-semantics recheck ----
  // one thread per row (256 threads, 256 rows): scan all 32 candidate keys.
  {
    const int rl = tid;               // row in block
    const unsigned* keys = dmp + rl * 33;
    unsigned mk = 0xFFFFFFFFu;
    for (int j = 0; j < 32; ++j) mk = umn(mk, keys[j]);
    // scaled margin 0.5 = 1.2e-4 unscaled: covers f16 cvt noise (RNE, ~5e-7),
    // e2 omission (2.6e-6), key truncation (1.9e-6), np fp32-grid ulp (7.6e-6)
    const float lim = __uint_as_float(mk & 0xFFFFFF00u) + 0.5f;

    const float4* zr4 = (const float4*)(z + (size_t)(row0 + rl) * Dn);

    // z2: np-pairwise grouping (argmin invariant to z2 rounding; keep identical)
    float r8[8];
#pragma unroll
    for (int g = 0; g < 2; ++g) {
      float4 v = zr4[g]; int j = g * 4;
      r8[j + 0] = __fmul_rn(v.x, v.x); r8[j + 1] = __fmul_rn(v.y, v.y);
      r8[j + 2] = __fmul_rn(v.z, v.z); r8[j + 3] = __fmul_rn(v.w, v.w);
    }
#pragma unroll
    for (int g = 2; g < 16; ++g) {
      float4 v = zr4[g]; int j = (g & 1) * 4;
      r8[j + 0] = __fadd_rn(r8[j + 0], __fmul_rn(v.x, v.x));
      r8[j + 1] = __fadd_rn(r8[j + 1], __fmul_rn(v.y, v.y));
      r8[j + 2] = __fadd_rn(r8[j + 2], __fmul_rn(v.z, v.z));
      r8[j + 3] = __fadd_rn(r8[j + 3], __fmul_rn(v.w, v.w));
    }
    float z2f = __fadd_rn(__fadd_rn(__fadd_rn(r8[0], r8[1]), __fadd_rn(r8[2], r8[3])),
                          __fadd_rn(__fadd_rn(r8[4], r8[5]), __fadd_rn(r8[6], r8[7])));

    float bq = INFINITY; int bc = Kn;
    for (int j = 0; j < 32; ++j) {
      unsigned key = keys[j];
      float sc = __uint_as_float(key & 0xFFFFFF00u);
      if (sc > lim) continue;
      int tag = (int)(key & 0xFFu);             // (t<<6)|kt
      int code = (tag & 63) * 64 + (tag >> 6) * 16 + (j >> 1);
      const float4* cr = (const float4*)(cb + (size_t)code * Dn);
      double ze = 0.0;
      float e8[8];
#pragma unroll
      for (int g = 0; g < 16; ++g) {
        float4 ev = cr[g]; float4 zv = zr4[g];
        ze += (double)ev.x * (double)zv.x + (double)ev.y * (double)zv.y +
              (double)ev.z * (double)zv.z + (double)ev.w * (double)zv.w;
        int jj = (g & 1) * 4;
        if (g < 2) {
          e8[jj + 0] = __fmul_rn(ev.x, ev.x); e8[jj + 1] = __fmul_rn(ev.y, ev.y);
          e8[jj + 2] = __fmul_rn(ev.z, ev.z); e8[jj + 3] = __fmul_rn(ev.w, ev.w);
        } else {
          e8[jj + 0] = __fadd_rn(e8[jj + 0], __fmul_rn(ev.x, ev.x));
          e8[jj + 1] = __fadd_rn(e8[jj + 1], __fmul_rn(ev.y, ev.y));
          e8[jj + 2] = __fadd_rn(e8[jj + 2], __fmul_rn(ev.z, ev.z));
          e8[jj + 3] = __fadd_rn(e8[jj + 3], __fmul_rn(ev.w, ev.w));
        }
      }
      float e2f = __fadd_rn(__fadd_rn(__fadd_rn(e8[0], e8[1]), __fadd_rn(e8[2], e8[3])),
                            __fadd_rn(__fadd_rn(e8[4], e8[5]), __fadd_rn(e8[6], e8[7])));
      // np semantics: qv = fl32( fl32(z2 + e2) - fl32(2*ze) )
      float zef = (float)ze;
      float t1 = __fadd_rn(z2f, e2f);
      float t2 = __fmul_rn(2.0f, zef);
      float qv = __fadd_rn(t1, -t2);
      if (qv < bq || (qv == bq && code < bc)) { bq = qv; bc = code; }
    }
    ((int*)(smem + 65536))[rl] = bc;
    out[(size_t)Bn * Dn + row0 + rl] = (float)bc;
  }
  __syncthreads();

  // ---- gather z_q = cb[winner], coalesced float4 ----
  {
    const float4* cb4 = (const float4*)cb;
    float4* out4 = (float4*)out;
    const int* wc = (const int*)(smem + 65536);
#pragma unroll
    for (int i = 0; i < 16; ++i) {
      int t = i * 256 + tid;
      int r = t >> 4, c2 = t & 15;
      int wn = wc[r];
      out4[(size_t)(row0 + r) * 16 + c2] = cb4[(size_t)wn * 16 + c2];
    }
  }
}

extern "C" void kernel_launch(void* const* d_in, const int* in_sizes, int n_in,
                              void* d_out, int out_size, void* d_ws, size_t ws_size,
                              hipStream_t stream) {
  const float* z = (const float*)d_in[0];
  const float* cb = (const float*)d_in[1];
  float* out = (float*)d_out;
  unsigned char* img = (unsigned char*)d_ws;   // needs 4096*64*2 = 512 KiB
  cvt_cb<<<128, 256, 0, stream>>>(cb, img);
  vq_main<<<Bn / 256, 256, 0, stream>>>(z, cb, img, out);
}